// Round 1
// baseline (2462.233 us; speedup 1.0000x reference)
//
#include <hip/hip_runtime.h>

typedef unsigned short u16;
typedef short short8 __attribute__((ext_vector_type(8)));
typedef float f32x4 __attribute__((ext_vector_type(4)));

// Problem constants
constexpr int B_  = 2;
constexpr int T_  = 256;
constexpr int V_  = 512;
constexpr int E_  = 768;
constexpr int L_  = 12;
constexpr int NH_ = 12;
constexpr int HD_ = 64;
constexpr int E3_ = 3 * E_;       // 2304
constexpr int E4_ = 4 * E_;       // 3072
constexpr int CPD_ = 2048;        // H_CP*V*R
constexpr int NTOK_ = B_ * T_;    // 512
constexpr int NVALID_ = B_ * (T_ - 2); // 508

__device__ __forceinline__ u16 f2b(float f) {  // RNE f32 -> bf16 bits
    union { float f; unsigned int u; } c; c.f = f;
    unsigned int r = (c.u + 0x7FFFu + ((c.u >> 16) & 1u)) >> 16; return (u16)r;
}

// -------------------- embed --------------------
__global__ __launch_bounds__(256) void embed_k(const int* __restrict__ ids,
    const float* __restrict__ wte, const float* __restrict__ wpe,
    float* __restrict__ h) {
    int n = blockIdx.x;
    int t = n % T_;
    int tok = ids[n];
    for (int e = threadIdx.x; e < E_; e += 256)
        h[n * E_ + e] = wte[tok * E_ + e] + wpe[t * E_ + e];
}

// -------------------- LayerNorm: fp32 in, bf16 out --------------------
__global__ __launch_bounds__(256) void ln_k(const float* __restrict__ in,
    const float* __restrict__ g, const float* __restrict__ bta,
    u16* __restrict__ out) {
    int n = blockIdx.x;
    int tid = threadIdx.x;
    const float* x = in + (size_t)n * E_;
    float v0 = x[tid], v1 = x[tid + 256], v2 = x[tid + 512];
    __shared__ float red[256];
    red[tid] = v0 + v1 + v2;
    __syncthreads();
    for (int o = 128; o > 0; o >>= 1) { if (tid < o) red[tid] += red[tid + o]; __syncthreads(); }
    float mean = red[0] * (1.0f / E_);
    __syncthreads();
    float d0 = v0 - mean, d1 = v1 - mean, d2 = v2 - mean;
    red[tid] = d0 * d0 + d1 * d1 + d2 * d2;
    __syncthreads();
    for (int o = 128; o > 0; o >>= 1) { if (tid < o) red[tid] += red[tid + o]; __syncthreads(); }
    float rstd = rsqrtf(red[0] * (1.0f / E_) + 1e-5f);
    u16* y = out + (size_t)n * E_;
    y[tid]       = f2b(d0 * rstd * g[tid]       + bta[tid]);
    y[tid + 256] = f2b(d1 * rstd * g[tid + 256] + bta[tid + 256]);
    y[tid + 512] = f2b(d2 * rstd * g[tid + 512] + bta[tid + 512]);
}

// -------------------- MFMA GEMM, 128x64 tile, 8 waves, split-K --------------------
// C[M x N] = A[M x K](bf16) @ W[K x N](fp32, row-major, converted+transposed into LDS on the fly)
// grid (N/64, M/128, KS); KC = K/KS (multiple of 32).
// mode 0: atomicAdd fp32 into outF (+bias from kz==0 block)
// mode 1: KS==1 only; v = gelu(acc+bias), store bf16 to outB
// LDS stride 40 elems (80 B) -> <=2-way bank aliasing on b128 reads (free).
// B-stage: 4 coalesced dword loads along N per thread, v_cvt_pk_bf16_f32 (RNE,
// bit-identical to f2b), one ds_write_b64 into transposed [n][k] layout.
__global__ __launch_bounds__(512) void mgemm_k(const u16* __restrict__ A,
    const float* __restrict__ W, const float* __restrict__ bias,
    float* __restrict__ outF, u16* __restrict__ outB,
    int K, int KC, int N, int mode) {
    __shared__ u16 As[128 * 40];
    __shared__ u16 Bs[64 * 40];
    int tid = threadIdx.x, lane = tid & 63, wid = tid >> 6;
    int ln15 = lane & 15, quad = lane >> 4;
    int col0 = blockIdx.x * 64, row0 = blockIdx.y * 128;
    int kz = blockIdx.z, kbase = kz * KC;
    int ar = tid >> 2, ak = (tid & 3) * 8;    // A: 128 rows x 32 k, uint4/thread
    const u16* Ag = A + (size_t)(row0 + ar) * K + kbase + ak;
    u16* Aw = &As[ar * 40 + ak];
    // B: thread owns col (tid&63), k-rows wk4..wk4+3
    int wk4 = (tid >> 6) * 4;                 // 0,4,...,28
    const float* Wg = W + (size_t)(kbase + wk4) * N + col0 + lane;
    u16* Bw = &Bs[lane * 40 + wk4];
    int wr = (wid >> 1) * 32, wc = (wid & 1) * 32;

    f32x4 zero = {0.f, 0.f, 0.f, 0.f};
    f32x4 acc[2][2];
    acc[0][0] = zero; acc[0][1] = zero; acc[1][0] = zero; acc[1][1] = zero;

    for (int k0 = 0; k0 < KC; k0 += 32) {
        uint4 av = *(const uint4*)(Ag + k0);
        float w0 = Wg[(size_t)(k0 + 0) * N];
        float w1 = Wg[(size_t)(k0 + 1) * N];
        float w2 = Wg[(size_t)(k0 + 2) * N];
        float w3 = Wg[(size_t)(k0 + 3) * N];
        unsigned int r0, r1;
        asm("v_cvt_pk_bf16_f32 %0, %1, %2" : "=v"(r0) : "v"(w0), "v"(w1));
        asm("v_cvt_pk_bf16_f32 %0, %1, %2" : "=v"(r1) : "v"(w2), "v"(w3));
        __syncthreads();
        *(uint4*)Aw = av;
        uint2 bw; bw.x = r0; bw.y = r1;
        *(uint2*)Bw = bw;
        __syncthreads();
        short8 af[2], bf[2];
#pragma unroll
        for (int mt = 0; mt < 2; mt++)
            af[mt] = *(const short8*)&As[(wr + mt * 16 + ln15) * 40 + quad * 8];
#pragma unroll
        for (int nt = 0; nt < 2; nt++)
            bf[nt] = *(const short8*)&Bs[(wc + nt * 16 + ln15) * 40 + quad * 8];
#pragma unroll
        for (int mt = 0; mt < 2; mt++)
#pragma unroll
            for (int nt = 0; nt < 2; nt++)
                acc[mt][nt] = __builtin_amdgcn_mfma_f32_16x16x32_bf16(
                    af[mt], bf[nt], acc[mt][nt], 0, 0, 0);
    }
    // C/D layout: col=lane&15, row=quad*4+reg (m89-verified, R4-proven)
#pragma unroll
    for (int mt = 0; mt < 2; mt++) {
#pragma unroll
        for (int nt = 0; nt < 2; nt++) {
            int c = col0 + wc + nt * 16 + ln15;
            if (mode == 0) {
                float bb = (kz == 0) ? bias[c] : 0.f;
#pragma unroll
                for (int r = 0; r < 4; r++) {
                    int rw = row0 + wr + mt * 16 + quad * 4 + r;
                    atomicAdd(&outF[(size_t)rw * N + c], acc[mt][nt][r] + bb);
                }
            } else {
                float bb = bias[c];
#pragma unroll
                for (int r = 0; r < 4; r++) {
                    int rw = row0 + wr + mt * 16 + quad * 4 + r;
                    float u = acc[mt][nt][r] + bb;
                    float inner = 0.7978845608028654f * (u + 0.044715f * u * u * u);
                    float v = 0.5f * u * (1.0f + tanhf(inner));
                    outB[(size_t)rw * N + c] = f2b(v);
                }
            }
        }
    }
}

// -------------------- Attention: fp32 qkv in, bf16 out; one block per (b,h,q) --------------------
__global__ __launch_bounds__(256) void attn_k(const float* __restrict__ qkv,
    u16* __restrict__ o) {
    int idx = blockIdx.x;
    int q = idx & (T_ - 1);
    int bh = idx >> 8;
    int h = bh % NH_, b = bh / NH_;
    int tid = threadIdx.x;
    __shared__ float qv[HD_];
    __shared__ float sc[T_];
    __shared__ float red[256];
    const float* qp = qkv + (size_t)(b * T_ + q) * E3_ + h * HD_;
    if (tid < HD_) qv[tid] = qp[tid];
    __syncthreads();
    int j = tid;
    const float* kp = qkv + (size_t)(b * T_ + j) * E3_ + E_ + h * HD_;
    float acc = 0.f;
#pragma unroll
    for (int d = 0; d < HD_; d++) acc += qv[d] * kp[d];
    float s = (j <= q) ? acc * 0.125f : -1e9f;
    red[tid] = s; __syncthreads();
    for (int off = 128; off > 0; off >>= 1) { if (tid < off) red[tid] = fmaxf(red[tid], red[tid + off]); __syncthreads(); }
    float m = red[0]; __syncthreads();
    float p = __expf(s - m);
    red[tid] = p; __syncthreads();
    for (int off = 128; off > 0; off >>= 1) { if (tid < off) red[tid] += red[tid + off]; __syncthreads(); }
    float Z = red[0]; __syncthreads();
    sc[j] = p / Z;
    __syncthreads();
    int d = tid & 63, chunk = tid >> 6;
    float part = 0.f;
    for (int jj = chunk * 64; jj < chunk * 64 + 64; jj++) {
        const float* vp = qkv + (size_t)(b * T_ + jj) * E3_ + 2 * E_ + h * HD_;
        part += sc[jj] * vp[d];
    }
    red[tid] = part; __syncthreads();
    if (tid < 64) {
        float val = red[tid] + red[tid + 64] + red[tid + 128] + red[tid + 192];
        o[(size_t)(b * T_ + q) * E_ + h * HD_ + tid] = f2b(val);
    }
}

// -------------------- Z / per-token loss --------------------
__global__ __launch_bounds__(256) void zloss_k(const float* __restrict__ cp,
    const int* __restrict__ ids, float* __restrict__ lossv) {
    int n = blockIdx.x;
    int b = n / (T_ - 2), t = n % (T_ - 2);
    int nf = b * T_ + t;
    const float* a = cp + (size_t)nf * CPD_;
    const float* bb = a + 1024;
    __shared__ float A0[V_], A1[V_], B0[V_], B1[V_];
    __shared__ float red[256];
    int tid = threadIdx.x;
    for (int v = tid; v < V_; v += 256) {
        A0[v] = a[2 * v]; A1[v] = a[2 * v + 1];
        B0[v] = bb[2 * v]; B1[v] = bb[2 * v + 1];
    }
    __syncthreads();
    float acc = 0.f;
    for (int j = tid; j < V_; j += 256) {
        float b0 = B0[j], b1 = B1[j];
        for (int i = 0; i < V_; i++)
            acc += __expf(A0[i] * b0 + A1[i] * b1);
    }
    red[tid] = acc; __syncthreads();
    for (int off = 128; off > 0; off >>= 1) { if (tid < off) red[tid] += red[tid + off]; __syncthreads(); }
    if (tid == 0) {
        int t0 = ids[b * T_ + t + 1];
        int t1 = ids[b * T_ + t + 2];
        float score = A0[t0] * B0[t1] + A1[t0] * B1[t1];
        lossv[n] = logf(red[0]) - score;
    }
}

// -------------------- final mean; dual-encoded scalar (absmax 0.0 proven in R3/R4) -----------
__global__ __launch_bounds__(256) void reduce_k(const float* __restrict__ lossv,
    unsigned int* __restrict__ out) {
    __shared__ float red[256];
    int tid = threadIdx.x;
    float s = 0.f;
    for (int i = tid; i < NVALID_; i += 256) s += lossv[i];
    red[tid] = s; __syncthreads();
    for (int off = 128; off > 0; off >>= 1) { if (tid < off) red[tid] += red[tid + off]; __syncthreads(); }
    if (tid == 0) {
        float loss = red[0] / (float)NVALID_;
        union { float f; unsigned int u; } cv; cv.f = loss;
        unsigned int b = (cv.u + 0x7FFFu + ((cv.u >> 16) & 1u)) >> 16;
        out[0] = (b << 16) | b;
    }
}

extern "C" void kernel_launch(void* const* d_in, const int* in_sizes, int n_in,
                              void* d_out, int out_size, void* d_ws, size_t ws_size,
                              hipStream_t stream) {
    const int*   ids  = (const int*)d_in[0];
    const float* wte  = (const float*)d_in[1];
    const float* wpe  = (const float*)d_in[2];
    const float* ln1g = (const float*)d_in[3];
    const float* ln1b = (const float*)d_in[4];
    const float* ln2g = (const float*)d_in[5];
    const float* ln2b = (const float*)d_in[6];
    const float* wqkv = (const float*)d_in[7];
    const float* bqkv = (const float*)d_in[8];
    const float* wao  = (const float*)d_in[9];
    const float* bao  = (const float*)d_in[10];
    const float* wfc  = (const float*)d_in[11];
    const float* bfc  = (const float*)d_in[12];
    const float* wmo  = (const float*)d_in[13];
    const float* bmo  = (const float*)d_in[14];
    const float* lnfg = (const float*)d_in[15];
    const float* lnfb = (const float*)d_in[16];
    const float* wcp  = (const float*)d_in[17];
    const float* bcp  = (const float*)d_in[18];

    // workspace layout (bytes) -- no weight slab needed anymore (~11 MB total)
    char* p = (char*)d_ws;
    float* h    = (float*)p; p += (size_t)NTOK_ * E_ * 4;      // 1.50 MB
    u16*   x    = (u16*)p;   p += (size_t)NTOK_ * E_ * 2;      // 0.75 MB
    u16*   aob  = (u16*)p;   p += (size_t)NTOK_ * E_ * 2;      // 0.75 MB
    u16*   fcb  = (u16*)p;   p += (size_t)NTOK_ * E4_ * 2;     // 3.0 MB
    float* bigF = (float*)p; p += (size_t)NTOK_ * E3_ * 4;     // 4.5 MB: qkvF / cpF (disjoint)
    float* lossv = (float*)p; p += 4096;
    float* qkvF = bigF;
    float* cpF  = bigF;

    embed_k<<<NTOK_, 256, 0, stream>>>(ids, wte, wpe, h);
    for (int l = 0; l < L_; l++) {
        ln_k<<<NTOK_, 256, 0, stream>>>(h, ln1g + l * E_, ln1b + l * E_, x);
        hipMemsetAsync(qkvF, 0, (size_t)NTOK_ * E3_ * 4, stream);
        mgemm_k<<<dim3(E3_ / 64, 4, 2), 512, 0, stream>>>(          // qkv: KS=2, KC=384
            x, wqkv + (size_t)l * E_ * E3_, bqkv + l * E3_, qkvF, nullptr, E_, 384, E3_, 0);
        attn_k<<<B_ * NH_ * T_, 256, 0, stream>>>(qkvF, aob);
        mgemm_k<<<dim3(E_ / 64, 4, 6), 512, 0, stream>>>(           // ao: KS=6, KC=128 -> h
            aob, wao + (size_t)l * E_ * E_, bao + l * E_, h, nullptr, E_, 128, E_, 0);
        ln_k<<<NTOK_, 256, 0, stream>>>(h, ln2g + l * E_, ln2b + l * E_, x);
        mgemm_k<<<dim3(E4_ / 64, 4, 1), 512, 0, stream>>>(          // fc: direct, gelu->bf16
            x, wfc + (size_t)l * E_ * E4_, bfc + l * E4_, nullptr, fcb, E_, 768, E4_, 1);
        mgemm_k<<<dim3(E_ / 64, 4, 8), 512, 0, stream>>>(           // mo: KS=8, KC=384 -> h
            fcb, wmo + (size_t)l * E4_ * E_, bmo + l * E_, h, nullptr, E4_, 384, E_, 0);
    }
    ln_k<<<NTOK_, 256, 0, stream>>>(h, lnfg, lnfb, x);
    hipMemsetAsync(cpF, 0, (size_t)NTOK_ * CPD_ * 4, stream);
    mgemm_k<<<dim3(CPD_ / 64, 4, 2), 512, 0, stream>>>(             // cp: KS=2, KC=384
        x, wcp, bcp, cpF, nullptr, E_, 384, CPD_, 0);
    zloss_k<<<NVALID_, 256, 0, stream>>>(cpF, ids, lossv);
    reduce_k<<<1, 256, 0, stream>>>(lossv, (unsigned int*)d_out);
}

// Round 2
// 1441.212 us; speedup vs baseline: 1.7084x; 1.7084x over previous
//
#include <hip/hip_runtime.h>

typedef unsigned short u16;
typedef short short8 __attribute__((ext_vector_type(8)));
typedef float f32x4 __attribute__((ext_vector_type(4)));

// Problem constants
constexpr int B_  = 2;
constexpr int T_  = 256;
constexpr int V_  = 512;
constexpr int E_  = 768;
constexpr int L_  = 12;
constexpr int NH_ = 12;
constexpr int HD_ = 64;
constexpr int E3_ = 3 * E_;       // 2304
constexpr int E4_ = 4 * E_;       // 3072
constexpr int CPD_ = 2048;        // H_CP*V*R
constexpr int NTOK_ = B_ * T_;    // 512
constexpr int NVALID_ = B_ * (T_ - 2); // 508

__device__ __forceinline__ u16 f2b(float f) {  // RNE f32 -> bf16 bits
    union { float f; unsigned int u; } c; c.f = f;
    unsigned int r = (c.u + 0x7FFFu + ((c.u >> 16) & 1u)) >> 16; return (u16)r;
}

// -------------------- embed --------------------
__global__ __launch_bounds__(256) void embed_k(const int* __restrict__ ids,
    const float* __restrict__ wte, const float* __restrict__ wpe,
    float* __restrict__ h) {
    int n = blockIdx.x;
    int t = n % T_;
    int tok = ids[n];
    for (int e = threadIdx.x; e < E_; e += 256)
        h[n * E_ + e] = wte[tok * E_ + e] + wpe[t * E_ + e];
}

// -------------------- LayerNorm: fp32 in, bf16 out --------------------
__global__ __launch_bounds__(256) void ln_k(const float* __restrict__ in,
    const float* __restrict__ g, const float* __restrict__ bta,
    u16* __restrict__ out) {
    int n = blockIdx.x;
    int tid = threadIdx.x;
    const float* x = in + (size_t)n * E_;
    float v0 = x[tid], v1 = x[tid + 256], v2 = x[tid + 512];
    __shared__ float red[256];
    red[tid] = v0 + v1 + v2;
    __syncthreads();
    for (int o = 128; o > 0; o >>= 1) { if (tid < o) red[tid] += red[tid + o]; __syncthreads(); }
    float mean = red[0] * (1.0f / E_);
    __syncthreads();
    float d0 = v0 - mean, d1 = v1 - mean, d2 = v2 - mean;
    red[tid] = d0 * d0 + d1 * d1 + d2 * d2;
    __syncthreads();
    for (int o = 128; o > 0; o >>= 1) { if (tid < o) red[tid] += red[tid + o]; __syncthreads(); }
    float rstd = rsqrtf(red[0] * (1.0f / E_) + 1e-5f);
    u16* y = out + (size_t)n * E_;
    y[tid]       = f2b(d0 * rstd * g[tid]       + bta[tid]);
    y[tid + 256] = f2b(d1 * rstd * g[tid + 256] + bta[tid + 256]);
    y[tid + 512] = f2b(d2 * rstd * g[tid + 512] + bta[tid + 512]);
}

// -------------------- MFMA GEMM, 128x64 tile, 8 waves, split-K --------------------
// C[M x N] = A[M x K](bf16) @ W[K x N](fp32, row-major, converted+transposed into LDS on the fly)
// grid (N/64, M/128, KS); KC = K/KS (multiple of 32).
// mode 0: atomicAdd fp32 into outF (+bias from kz==0 block)
// mode 1: KS==1 only; v = gelu(acc+bias), store bf16 to outB
__global__ __launch_bounds__(512) void mgemm_k(const u16* __restrict__ A,
    const float* __restrict__ W, const float* __restrict__ bias,
    float* __restrict__ outF, u16* __restrict__ outB,
    int K, int KC, int N, int mode) {
    __shared__ u16 As[128 * 40];
    __shared__ u16 Bs[64 * 40];
    int tid = threadIdx.x, lane = tid & 63, wid = tid >> 6;
    int ln15 = lane & 15, quad = lane >> 4;
    int col0 = blockIdx.x * 64, row0 = blockIdx.y * 128;
    int kz = blockIdx.z, kbase = kz * KC;
    int ar = tid >> 2, ak = (tid & 3) * 8;    // A: 128 rows x 32 k, uint4/thread
    const u16* Ag = A + (size_t)(row0 + ar) * K + kbase + ak;
    u16* Aw = &As[ar * 40 + ak];
    // B: thread owns col (tid&63), k-rows wk4..wk4+3
    int wk4 = (tid >> 6) * 4;                 // 0,4,...,28
    const float* Wg = W + (size_t)(kbase + wk4) * N + col0 + lane;
    u16* Bw = &Bs[lane * 40 + wk4];
    int wr = (wid >> 1) * 32, wc = (wid & 1) * 32;

    f32x4 zero = {0.f, 0.f, 0.f, 0.f};
    f32x4 acc[2][2];
    acc[0][0] = zero; acc[0][1] = zero; acc[1][0] = zero; acc[1][1] = zero;

    for (int k0 = 0; k0 < KC; k0 += 32) {
        uint4 av = *(const uint4*)(Ag + k0);
        float w0 = Wg[(size_t)(k0 + 0) * N];
        float w1 = Wg[(size_t)(k0 + 1) * N];
        float w2 = Wg[(size_t)(k0 + 2) * N];
        float w3 = Wg[(size_t)(k0 + 3) * N];
        unsigned int r0, r1;
        asm("v_cvt_pk_bf16_f32 %0, %1, %2" : "=v"(r0) : "v"(w0), "v"(w1));
        asm("v_cvt_pk_bf16_f32 %0, %1, %2" : "=v"(r1) : "v"(w2), "v"(w3));
        __syncthreads();
        *(uint4*)Aw = av;
        uint2 bw; bw.x = r0; bw.y = r1;
        *(uint2*)Bw = bw;
        __syncthreads();
        short8 af[2], bf[2];
#pragma unroll
        for (int mt = 0; mt < 2; mt++)
            af[mt] = *(const short8*)&As[(wr + mt * 16 + ln15) * 40 + quad * 8];
#pragma unroll
        for (int nt = 0; nt < 2; nt++)
            bf[nt] = *(const short8*)&Bs[(wc + nt * 16 + ln15) * 40 + quad * 8];
#pragma unroll
        for (int mt = 0; mt < 2; mt++)
#pragma unroll
            for (int nt = 0; nt < 2; nt++)
                acc[mt][nt] = __builtin_amdgcn_mfma_f32_16x16x32_bf16(
                    af[mt], bf[nt], acc[mt][nt], 0, 0, 0);
    }
    // C/D layout: col=lane&15, row=quad*4+reg (m89-verified, R4-proven)
#pragma unroll
    for (int mt = 0; mt < 2; mt++) {
#pragma unroll
        for (int nt = 0; nt < 2; nt++) {
            int c = col0 + wc + nt * 16 + ln15;
            if (mode == 0) {
                float bb = (kz == 0) ? bias[c] : 0.f;
#pragma unroll
                for (int r = 0; r < 4; r++) {
                    int rw = row0 + wr + mt * 16 + quad * 4 + r;
                    atomicAdd(&outF[(size_t)rw * N + c], acc[mt][nt][r] + bb);
                }
            } else {
                float bb = bias[c];
#pragma unroll
                for (int r = 0; r < 4; r++) {
                    int rw = row0 + wr + mt * 16 + quad * 4 + r;
                    float u = acc[mt][nt][r] + bb;
                    float inner = 0.7978845608028654f * (u + 0.044715f * u * u * u);
                    float v = 0.5f * u * (1.0f + tanhf(inner));
                    outB[(size_t)rw * N + c] = f2b(v);
                }
            }
        }
    }
}

// -------------------- MFMA flash attention --------------------
// grid (4 q-tiles of 64, B*NH), 256 threads (4 waves).
// Per block: stage K[256][64]+V^T[64][256] bf16 in LDS, Q frags from global.
// Wave w owns q-rows qt*64 + w*16 .. +15.
// S = Q.K^T (16x16x32 MFMA, same frag layout as mgemm: A/B frag lane=ln15->row,
// quad*8->k-octet; C: col=ln15(+16nt), row=quad*4+r). Masked softmax fully
// in-register (row spread over 16 ln15 lanes only -> shfl_xor 1/2/4/8).
// P -> LDS bf16 (transpose to A-frag layout), O = P.V via MFMA vs V^T.
constexpr int KSTR_ = 72;   // K LDS row stride (elems): 144B -> 2-way bank alias (free)
constexpr int PSTR_ = 264;  // P/Vt LDS row stride: 528B -> 2-way
__global__ __launch_bounds__(256) void fattn_k(const float* __restrict__ qkv,
    u16* __restrict__ o) {
    __shared__ u16 Ks[256 * KSTR_];   // 36864 B
    __shared__ u16 Vt[64 * PSTR_];    // 33792 B
    __shared__ u16 Ps[64 * PSTR_];    // 33792 B
    int qt = blockIdx.x;
    int bh = blockIdx.y;
    int hh = bh % NH_, b = bh / NH_;
    int tid = threadIdx.x, lane = tid & 63, wid = tid >> 6;
    int ln15 = lane & 15, quad = lane >> 4;

    // ---- stage K, V^T ----
    int sr = tid >> 4, sd = (tid & 15) * 4;      // 16 rows/pass, 4 d-elems/thread
    const float* Kg = qkv + (size_t)(b * T_) * E3_ + E_ + hh * HD_;
    const float* Vg = qkv + (size_t)(b * T_) * E3_ + 2 * E_ + hh * HD_;
#pragma unroll
    for (int pass = 0; pass < 16; pass++) {
        int rr = sr + pass * 16;
        float4 kv = *(const float4*)&Kg[(size_t)rr * E3_ + sd];
        unsigned int c0, c1;
        asm("v_cvt_pk_bf16_f32 %0, %1, %2" : "=v"(c0) : "v"(kv.x), "v"(kv.y));
        asm("v_cvt_pk_bf16_f32 %0, %1, %2" : "=v"(c1) : "v"(kv.z), "v"(kv.w));
        uint2 pk; pk.x = c0; pk.y = c1;
        *(uint2*)&Ks[rr * KSTR_ + sd] = pk;
        float4 vv = *(const float4*)&Vg[(size_t)rr * E3_ + sd];
        Vt[(sd + 0) * PSTR_ + rr] = f2b(vv.x);
        Vt[(sd + 1) * PSTR_ + rr] = f2b(vv.y);
        Vt[(sd + 2) * PSTR_ + rr] = f2b(vv.z);
        Vt[(sd + 3) * PSTR_ + rr] = f2b(vv.w);
    }

    // ---- Q fragments straight to registers ----
    const float* Qg = qkv + (size_t)(b * T_ + qt * 64 + wid * 16 + ln15) * E3_ + hh * HD_;
    short8 qf[2];
#pragma unroll
    for (int ks = 0; ks < 2; ks++) {
        const float* qp = Qg + ks * 32 + quad * 8;
        union { short8 s8; unsigned int u[4]; } uq;
#pragma unroll
        for (int i = 0; i < 4; i++) {
            float a0 = qp[2 * i], a1 = qp[2 * i + 1];
            asm("v_cvt_pk_bf16_f32 %0, %1, %2" : "=v"(uq.u[i]) : "v"(a0), "v"(a1));
        }
        qf[ks] = uq.s8;
    }

    __syncthreads();

    // ---- S = Q.K^T : wave computes 16 q-rows x 256 cols ----
    f32x4 s[16];
#pragma unroll
    for (int nt = 0; nt < 16; nt++) s[nt] = (f32x4){0.f, 0.f, 0.f, 0.f};
#pragma unroll
    for (int ks = 0; ks < 2; ks++) {
#pragma unroll
        for (int nt = 0; nt < 16; nt++) {
            short8 kf = *(const short8*)&Ks[(nt * 16 + ln15) * KSTR_ + ks * 32 + quad * 8];
            s[nt] = __builtin_amdgcn_mfma_f32_16x16x32_bf16(qf[ks], kf, s[nt], 0, 0, 0);
        }
    }

    // ---- masked softmax, in-register per row ----
#pragma unroll
    for (int r = 0; r < 4; r++) {
        int q = qt * 64 + wid * 16 + quad * 4 + r;
        float m = -1e30f;
#pragma unroll
        for (int nt = 0; nt < 16; nt++) {
            int j = nt * 16 + ln15;
            float sv = (j <= q) ? s[nt][r] * 0.125f : -1e9f;
            s[nt][r] = sv;
            m = fmaxf(m, sv);
        }
        m = fmaxf(m, __shfl_xor(m, 1));
        m = fmaxf(m, __shfl_xor(m, 2));
        m = fmaxf(m, __shfl_xor(m, 4));
        m = fmaxf(m, __shfl_xor(m, 8));
        float sum = 0.f;
#pragma unroll
        for (int nt = 0; nt < 16; nt++) {
            float p = __expf(s[nt][r] - m);
            s[nt][r] = p;
            sum += p;
        }
        sum += __shfl_xor(sum, 1);
        sum += __shfl_xor(sum, 2);
        sum += __shfl_xor(sum, 4);
        sum += __shfl_xor(sum, 8);
        float inv = 1.0f / sum;
#pragma unroll
        for (int nt = 0; nt < 16; nt++) s[nt][r] *= inv;
    }

    // ---- P -> LDS (bf16, A-frag layout rows) ----
#pragma unroll
    for (int nt = 0; nt < 16; nt++)
#pragma unroll
        for (int r = 0; r < 4; r++)
            Ps[(wid * 16 + quad * 4 + r) * PSTR_ + nt * 16 + ln15] = f2b(s[nt][r]);

    __syncthreads();

    // ---- O = P.V : 16 rows x 64 cols per wave ----
    f32x4 oacc[4];
#pragma unroll
    for (int dt = 0; dt < 4; dt++) oacc[dt] = (f32x4){0.f, 0.f, 0.f, 0.f};
#pragma unroll
    for (int ks = 0; ks < 8; ks++) {
        short8 pf = *(const short8*)&Ps[(wid * 16 + ln15) * PSTR_ + ks * 32 + quad * 8];
#pragma unroll
        for (int dt = 0; dt < 4; dt++) {
            short8 vf = *(const short8*)&Vt[(dt * 16 + ln15) * PSTR_ + ks * 32 + quad * 8];
            oacc[dt] = __builtin_amdgcn_mfma_f32_16x16x32_bf16(pf, vf, oacc[dt], 0, 0, 0);
        }
    }

    // ---- store O bf16 ----
#pragma unroll
    for (int dt = 0; dt < 4; dt++) {
#pragma unroll
        for (int r = 0; r < 4; r++) {
            int q = qt * 64 + wid * 16 + quad * 4 + r;
            o[(size_t)(b * T_ + q) * E_ + hh * HD_ + dt * 16 + ln15] = f2b(oacc[dt][r]);
        }
    }
}

// -------------------- Z / per-token loss --------------------
__global__ __launch_bounds__(256) void zloss_k(const float* __restrict__ cp,
    const int* __restrict__ ids, float* __restrict__ lossv) {
    int n = blockIdx.x;
    int b = n / (T_ - 2), t = n % (T_ - 2);
    int nf = b * T_ + t;
    const float* a = cp + (size_t)nf * CPD_;
    const float* bb = a + 1024;
    __shared__ float A0[V_], A1[V_], B0[V_], B1[V_];
    __shared__ float red[256];
    int tid = threadIdx.x;
    for (int v = tid; v < V_; v += 256) {
        A0[v] = a[2 * v]; A1[v] = a[2 * v + 1];
        B0[v] = bb[2 * v]; B1[v] = bb[2 * v + 1];
    }
    __syncthreads();
    float acc = 0.f;
    for (int j = tid; j < V_; j += 256) {
        float b0 = B0[j], b1 = B1[j];
        for (int i = 0; i < V_; i++)
            acc += __expf(A0[i] * b0 + A1[i] * b1);
    }
    red[tid] = acc; __syncthreads();
    for (int off = 128; off > 0; off >>= 1) { if (tid < off) red[tid] += red[tid + off]; __syncthreads(); }
    if (tid == 0) {
        int t0 = ids[b * T_ + t + 1];
        int t1 = ids[b * T_ + t + 2];
        float score = A0[t0] * B0[t1] + A1[t0] * B1[t1];
        lossv[n] = logf(red[0]) - score;
    }
}

// -------------------- final mean; dual-encoded scalar --------------------
__global__ __launch_bounds__(256) void reduce_k(const float* __restrict__ lossv,
    unsigned int* __restrict__ out) {
    __shared__ float red[256];
    int tid = threadIdx.x;
    float s = 0.f;
    for (int i = tid; i < NVALID_; i += 256) s += lossv[i];
    red[tid] = s; __syncthreads();
    for (int off = 128; off > 0; off >>= 1) { if (tid < off) red[tid] += red[tid + off]; __syncthreads(); }
    if (tid == 0) {
        float loss = red[0] / (float)NVALID_;
        union { float f; unsigned int u; } cv; cv.f = loss;
        unsigned int b = (cv.u + 0x7FFFu + ((cv.u >> 16) & 1u)) >> 16;
        out[0] = (b << 16) | b;
    }
}

extern "C" void kernel_launch(void* const* d_in, const int* in_sizes, int n_in,
                              void* d_out, int out_size, void* d_ws, size_t ws_size,
                              hipStream_t stream) {
    const int*   ids  = (const int*)d_in[0];
    const float* wte  = (const float*)d_in[1];
    const float* wpe  = (const float*)d_in[2];
    const float* ln1g = (const float*)d_in[3];
    const float* ln1b = (const float*)d_in[4];
    const float* ln2g = (const float*)d_in[5];
    const float* ln2b = (const float*)d_in[6];
    const float* wqkv = (const float*)d_in[7];
    const float* bqkv = (const float*)d_in[8];
    const float* wao  = (const float*)d_in[9];
    const float* bao  = (const float*)d_in[10];
    const float* wfc  = (const float*)d_in[11];
    const float* bfc  = (const float*)d_in[12];
    const float* wmo  = (const float*)d_in[13];
    const float* bmo  = (const float*)d_in[14];
    const float* lnfg = (const float*)d_in[15];
    const float* lnfb = (const float*)d_in[16];
    const float* wcp  = (const float*)d_in[17];
    const float* bcp  = (const float*)d_in[18];

    // workspace layout (bytes) -- ~11 MB total
    char* p = (char*)d_ws;
    float* h    = (float*)p; p += (size_t)NTOK_ * E_ * 4;      // 1.50 MB
    u16*   x    = (u16*)p;   p += (size_t)NTOK_ * E_ * 2;      // 0.75 MB
    u16*   aob  = (u16*)p;   p += (size_t)NTOK_ * E_ * 2;      // 0.75 MB
    u16*   fcb  = (u16*)p;   p += (size_t)NTOK_ * E4_ * 2;     // 3.0 MB
    float* bigF = (float*)p; p += (size_t)NTOK_ * E3_ * 4;     // 4.5 MB: qkvF / cpF (disjoint)
    float* lossv = (float*)p; p += 4096;
    float* qkvF = bigF;
    float* cpF  = bigF;

    embed_k<<<NTOK_, 256, 0, stream>>>(ids, wte, wpe, h);
    for (int l = 0; l < L_; l++) {
        ln_k<<<NTOK_, 256, 0, stream>>>(h, ln1g + l * E_, ln1b + l * E_, x);
        hipMemsetAsync(qkvF, 0, (size_t)NTOK_ * E3_ * 4, stream);
        mgemm_k<<<dim3(E3_ / 64, 4, 2), 512, 0, stream>>>(          // qkv: KS=2, KC=384
            x, wqkv + (size_t)l * E_ * E3_, bqkv + l * E3_, qkvF, nullptr, E_, 384, E3_, 0);
        fattn_k<<<dim3(4, B_ * NH_), 256, 0, stream>>>(qkvF, aob);
        mgemm_k<<<dim3(E_ / 64, 4, 6), 512, 0, stream>>>(           // ao: KS=6, KC=128 -> h
            aob, wao + (size_t)l * E_ * E_, bao + l * E_, h, nullptr, E_, 128, E_, 0);
        ln_k<<<NTOK_, 256, 0, stream>>>(h, ln2g + l * E_, ln2b + l * E_, x);
        mgemm_k<<<dim3(E4_ / 64, 4, 1), 512, 0, stream>>>(          // fc: direct, gelu->bf16
            x, wfc + (size_t)l * E_ * E4_, bfc + l * E4_, nullptr, fcb, E_, 768, E4_, 1);
        mgemm_k<<<dim3(E_ / 64, 4, 8), 512, 0, stream>>>(           // mo: KS=8, KC=384 -> h
            fcb, wmo + (size_t)l * E4_ * E_, bmo + l * E_, h, nullptr, E4_, 384, E_, 0);
    }
    ln_k<<<NTOK_, 256, 0, stream>>>(h, lnfg, lnfb, x);
    hipMemsetAsync(cpF, 0, (size_t)NTOK_ * CPD_ * 4, stream);
    mgemm_k<<<dim3(CPD_ / 64, 4, 2), 512, 0, stream>>>(             // cp: KS=2, KC=384
        x, wcp, bcp, cpF, nullptr, E_, 384, CPD_, 0);
    zloss_k<<<NVALID_, 256, 0, stream>>>(cpF, ids, lossv);
    reduce_k<<<1, 256, 0, stream>>>(lossv, (unsigned int*)d_out);
}